// Round 4
// baseline (27355.215 us; speedup 1.0000x reference)
//
#include <hip/hip_runtime.h>
#include <hip/hip_cooperative_groups.h>
#include <math.h>

namespace cg = cooperative_groups;

#define B   256
#define TX  50
#define TY  100
#define NX  64
#define NY  64
#define H   512
#define HOR 60
#define M1  1024
#define M2  512
#define G3  (3*H)        // 1536
#define DIN (2*H + NY)   // 1088

typedef __attribute__((ext_vector_type(8))) short short8;
typedef __attribute__((ext_vector_type(4))) float floatx4;

__device__ __forceinline__ unsigned short f2bf(float f) {
    union { float f; unsigned u; } v; v.f = f;
    return (unsigned short)((v.u + 0x7FFFu + ((v.u >> 16) & 1u)) >> 16);
}

__device__ __forceinline__ float sigmoidf_(float v) {
    return 1.f / (1.f + __expf(-v));
}

__device__ __forceinline__ short8 ld8(const unsigned short* p) {
    return *(const short8*)p;
}

__device__ __forceinline__ floatx4 mfma16(short8 a, short8 b, floatx4 c) {
    return __builtin_amdgcn_mfma_f32_16x16x32_bf16(a, b, c, 0, 0, 0);
}

__device__ __forceinline__ void gload_lds16(const void* g, void* lds) {
    __builtin_amdgcn_global_load_lds(
        (const __attribute__((address_space(1))) void*)g,
        (__attribute__((address_space(3))) void*)lds, 16, 0, 0);
}

// ===========================================================================
// r2-proven 128x128 MFMA GEMM (one-shot bottleneck layers only)
// ===========================================================================
template<int BM, int BN>
__device__ __forceinline__ void mgemm_body(
    unsigned short* smA, unsigned short* smB,
    const unsigned short* __restrict__ A, int lda, int arow0,
    const unsigned short* __restrict__ W, int ldw, int wrow0,
    const float* __restrict__ bias,
    float* __restrict__ Cf, int ldcf,
    unsigned short* __restrict__ Cb, int ldcb,
    int K, int relu)
{
    constexpr int MF = BM / 32;
    constexpr int NF = BN / 32;
    const int tid = threadIdx.x;
    const int w  = tid >> 6, l = tid & 63;
    const int wr = w >> 1, wc = w & 1;
    const int lg = l >> 4, r16 = l & 15;

    floatx4 acc[MF][NF];
#pragma unroll
    for (int m = 0; m < MF; ++m)
#pragma unroll
        for (int n = 0; n < NF; ++n) acc[m][n] = floatx4{0.f, 0.f, 0.f, 0.f};

    for (int k0 = 0; k0 < K; k0 += 32) {
        __syncthreads();
#pragma unroll
        for (int i = 0; i < BM / 64; ++i) {
            const int ci = tid + i * 256;
            const int row = ci >> 2, pc = ci & 3;
            const int lc = pc ^ ((row >> 1) & 3);
            gload_lds16(A + (size_t)(arow0 + row) * lda + k0 + lc * 8,
                        (char*)smA + w * 1024 + i * 4096);
        }
#pragma unroll
        for (int i = 0; i < BN / 64; ++i) {
            const int ci = tid + i * 256;
            const int row = ci >> 2, pc = ci & 3;
            const int lc = pc ^ ((row >> 1) & 3);
            gload_lds16(W + (size_t)(wrow0 + row) * ldw + k0 + lc * 8,
                        (char*)smB + w * 1024 + i * 4096);
        }
        __syncthreads();

        short8 af[MF], bfr[NF];
#pragma unroll
        for (int m = 0; m < MF; ++m) {
            const int row = wr * (BM / 2) + m * 16 + r16;
            const int pc = lg ^ ((row >> 1) & 3);
            af[m] = *(const short8*)&smA[row * 32 + pc * 8];
        }
#pragma unroll
        for (int n = 0; n < NF; ++n) {
            const int row = wc * (BN / 2) + n * 16 + r16;
            const int pc = lg ^ ((row >> 1) & 3);
            bfr[n] = *(const short8*)&smB[row * 32 + pc * 8];
        }
#pragma unroll
        for (int m = 0; m < MF; ++m)
#pragma unroll
            for (int n = 0; n < NF; ++n)
                acc[m][n] = mfma16(af[m], bfr[n], acc[m][n]);
    }

#pragma unroll
    for (int m = 0; m < MF; ++m) {
#pragma unroll
        for (int n = 0; n < NF; ++n) {
#pragma unroll
            for (int j = 0; j < 4; ++j) {
                const int r = arow0 + wr * (BM / 2) + m * 16 + lg * 4 + j;
                const int c = wrow0 + wc * (BN / 2) + n * 16 + r16;
                float v = acc[m][n][j];
                if (bias) v += bias[c];
                if (relu && v < 0.f) v = 0.f;
                if (Cf) Cf[(size_t)r * ldcf + c] = v;
                if (Cb) Cb[(size_t)r * ldcb + c] = f2bf(v);
            }
        }
    }
}

template<int BM, int BN>
__global__ __launch_bounds__(256) void k_mgemm(
    const unsigned short* __restrict__ A, int lda,
    const unsigned short* __restrict__ W, int ldw,
    const float* __restrict__ bias,
    float* __restrict__ Cf, int ldcf,
    unsigned short* __restrict__ Cb, int ldcb,
    int K, int relu)
{
    __shared__ __align__(16) unsigned short smA[BM * 32];
    __shared__ __align__(16) unsigned short smB[BN * 32];
    mgemm_body<BM, BN>(smA, smB, A, lda, blockIdx.y * BM,
                       W, ldw, blockIdx.x * BN, bias,
                       Cf, ldcf, Cb, ldcb, K, relu);
}

// ===========================================================================
// fused fp32 -> bf16 conversion (18 segments, one launch)
// ===========================================================================
struct CvtArgs {
    const float* src[18];
    unsigned short* dst[18];
    int n[18];
};

__global__ __launch_bounds__(256) void k_cvt_all(CvtArgs a)
{
    const int seg = blockIdx.y;
    const float* s = a.src[seg];
    unsigned short* d = a.dst[seg];
    const int c4 = a.n[seg] >> 2;
    for (int i = blockIdx.x * 256 + threadIdx.x; i < c4; i += gridDim.x * 256) {
        float4 v = ((const float4*)s)[i];
        ushort4 o;
        o.x = f2bf(v.x); o.y = f2bf(v.y); o.z = f2bf(v.z); o.w = f2bf(v.w);
        ((ushort4*)d)[i] = o;
    }
}

// ===========================================================================
// h_x = hxf + hxb ; h_y = hef + heb ; hcat = [h_x,h_y] bf16 ; cz[:, :H] = h_x
// ===========================================================================
__global__ __launch_bounds__(256) void k_sum_concat(
    const float* __restrict__ Hs,
    unsigned short* __restrict__ hcatb, unsigned short* __restrict__ czb)
{
    const int idx = blockIdx.x * 256 + threadIdx.x;  // B*H
    const int b = idx / H, i = idx % H;
    const float hx = Hs[idx] + Hs[(size_t)B * H + idx];
    const float hy = Hs[2 * (size_t)B * H + idx] + Hs[3 * (size_t)B * H + idx];
    const unsigned short hxb = f2bf(hx);
    hcatb[(size_t)b * (2 * H) + i] = hxb;
    hcatb[(size_t)b * (2 * H) + H + i] = f2bf(hy);
    czb[(size_t)b * (2 * H) + i] = hxb;
}

// ===========================================================================
// Persistent encoder — ZERO LDS, all-register fragments.
// 256 blocks = job(4) x batch-half(2) x hidden-slice(32); 512 threads = 8
// waves x 16 batch rows. Block owns 48 gate cols (3 gates x 16 hidden):
// col-frag n == gate n, lane r16 == hidden unit -> gates computed directly
// from MFMA accumulators. h state + input-weight frags live in registers
// across all 100 steps. 1 grid sync per step.
// ===========================================================================
struct EncArgs {
    const unsigned short *xb, *yb;
    unsigned short *Hsb0, *Hsb1;   // bf16 h ping-pong, [4][B][H]
    float* Hs;                     // final fp32 h, [4][B][H]
    const unsigned short* wih[4];
    const unsigned short* whh[4];
    const float* bih[4];
    const float* bhh[4];
};

__global__ __launch_bounds__(512) void k_enc(EncArgs a)
{
    const int bid = blockIdx.x;
    const int job = bid >> 6, bg = (bid >> 5) & 1, hs = bid & 31;
    const int tid = threadIdx.x;
    const int w = tid >> 6, l = tid & 63;
    const int lg = l >> 4, r16 = l & 15;
    const int T = (job < 2) ? TX : TY;
    const bool rev = job & 1;
    const unsigned short* xsrc = (job < 2) ? a.xb : a.yb;
    const unsigned short* wihg = a.wih[job];
    const unsigned short* whhg = a.whh[job];
    const int arow = bg * 128 + w * 16 + r16;   // A-fragment row (this lane)
    const int crow = bg * 128 + w * 16 + lg * 4; // C row base (j offset)
    const int ic = hs * 16 + r16;                // hidden unit (this lane)

    float bihv[3], bhhv[3];
#pragma unroll
    for (int g = 0; g < 3; ++g) {
        bihv[g] = a.bih[job][g * H + ic];
        bhhv[g] = a.bhh[job][g * H + ic];
    }
    short8 xw[2][3];   // loop-invariant input-weight fragments
#pragma unroll
    for (int ks = 0; ks < 2; ++ks)
#pragma unroll
        for (int n = 0; n < 3; ++n)
            xw[ks][n] = ld8(wihg + (size_t)(n * H + ic) * NX + ks * 32 + lg * 8);

    float hst[4] = {0.f, 0.f, 0.f, 0.f};
    cg::grid_group gg = cg::this_grid();

    for (int t = 0; t < TY; ++t) {
        if (t < T) {
            const int tt = rev ? (T - 1 - t) : t;
            const short8 xa0 = ld8(xsrc + ((size_t)arow * T + tt) * NX + lg * 8);
            const short8 xa1 = ld8(xsrc + ((size_t)arow * T + tt) * NX + 32 + lg * 8);

            floatx4 ax[3], ah[3];
#pragma unroll
            for (int n = 0; n < 3; ++n) {
                ax[n] = floatx4{0.f, 0.f, 0.f, 0.f};
                ah[n] = floatx4{0.f, 0.f, 0.f, 0.f};
            }
#pragma unroll
            for (int n = 0; n < 3; ++n) {
                ax[n] = mfma16(xa0, xw[0][n], ax[n]);
                ax[n] = mfma16(xa1, xw[1][n], ax[n]);
            }

            const unsigned short* hsb =
                ((t & 1) ? a.Hsb1 : a.Hsb0) + (size_t)job * B * H;
#pragma unroll 4
            for (int c = 0; c < 16; ++c) {
                const short8 ha = ld8(hsb + (size_t)arow * H + c * 32 + lg * 8);
#pragma unroll
                for (int n = 0; n < 3; ++n) {
                    const short8 hw =
                        ld8(whhg + (size_t)(n * H + ic) * H + c * 32 + lg * 8);
                    ah[n] = mfma16(ha, hw, ah[n]);
                }
            }

            unsigned short* ho =
                ((t & 1) ? a.Hsb0 : a.Hsb1) + (size_t)job * B * H;
#pragma unroll
            for (int j = 0; j < 4; ++j) {
                const float r  = sigmoidf_(ax[0][j] + bihv[0] + ah[0][j] + bhhv[0]);
                const float z  = sigmoidf_(ax[1][j] + bihv[1] + ah[1][j] + bhhv[1]);
                const float nn = tanhf(ax[2][j] + bihv[2] + r * (ah[2][j] + bhhv[2]));
                hst[j] = (1.f - z) * nn + z * hst[j];
                ho[(size_t)(crow + j) * H + ic] = f2bf(hst[j]);
            }
        }
        __threadfence();
        gg.sync();
    }

#pragma unroll
    for (int j = 0; j < 4; ++j)
        a.Hs[(size_t)job * B * H + (size_t)(crow + j) * H + ic] = hst[j];
}

// ===========================================================================
// Persistent decoder — ZERO LDS. 256 blocks x 512 threads, 60 steps x 4
// sync-slots. Recurrent pre-activation hga and hd state stay in registers
// of blocks 0-63 across the whole horizon.
//   slot1: xgd (K=64) + gates          blocks 0-63
//   slot2: hga_next (K=512)            blocks 0-63   || MLP1   blocks 64-191
//   slot3: MLP2                        blocks 128-191
//   slot4: out -> y fp32 + bf16        blocks 192-199
// ===========================================================================
struct DecArgs {
    const unsigned short* xb;
    unsigned short* ypb;
    unsigned short* hdb;
    const float* constb;
    const unsigned short* dWihb;
    const unsigned short* dWhhb;
    const float* dbhh;
    const unsigned short* dmW1b; const float* dmb1;
    const unsigned short* dmW2b; const float* dmb2;
    const unsigned short* doWb;  const float* dob;
    unsigned short* hm1b; unsigned short* hm2b;
    float* outp;
};

__global__ __launch_bounds__(512) void k_dec(DecArgs a)
{
    const int bid = blockIdx.x, tid = threadIdx.x;
    const int w = tid >> 6, l = tid & 63;
    const int lg = l >> 4, r16 = l & 15;
    cg::grid_group gg = cg::this_grid();

    // ---- GRU role (blocks 0-63) ----
    const int bg = (bid >> 5) & 1, hs = bid & 31;
    const int g_arow = bg * 128 + w * 16 + r16;
    const int g_crow = bg * 128 + w * 16 + lg * 4;
    const int g_ic = hs * 16 + r16;
    float cst[3][4], dbhhv[3];
    short8 xw[2][3];
    float hd[4] = {0.f, 0.f, 0.f, 0.f};
    floatx4 hga[3];
    if (bid < 64) {
#pragma unroll
        for (int n = 0; n < 3; ++n) {
            dbhhv[n] = a.dbhh[n * H + g_ic];
            hga[n] = floatx4{0.f, 0.f, 0.f, 0.f};
#pragma unroll
            for (int j = 0; j < 4; ++j)
                cst[n][j] = a.constb[(size_t)(g_crow + j) * G3 + n * H + g_ic];
#pragma unroll
            for (int ks = 0; ks < 2; ++ks)
                xw[ks][n] = ld8(a.dWihb + (size_t)(n * H + g_ic) * DIN
                                        + 2 * H + ks * 32 + lg * 8);
        }
    }
    // ---- MLP1 role (blocks 64-191): 64x32 tile, waves 4r x 2c ----
    const int m1_r0 = ((bid - 64) >> 5) * 64;
    const int m1_ar = m1_r0 + (w >> 1) * 16 + r16;
    const int m1_cr = m1_r0 + (w >> 1) * 16 + lg * 4;
    const int m1_c  = ((bid - 64) & 31) * 32 + (w & 1) * 16 + r16;
    // ---- MLP2 role (blocks 128-191): 64x32 tile ----
    const int m2_r0 = ((bid - 128) >> 4) * 64;
    const int m2_ar = m2_r0 + (w >> 1) * 16 + r16;
    const int m2_cr = m2_r0 + (w >> 1) * 16 + lg * 4;
    const int m2_c  = ((bid - 128) & 15) * 32 + (w & 1) * 16 + r16;
    // ---- OUT role (blocks 192-199): 64x32 tile ----
    const int o_r0 = ((bid - 192) >> 1) * 64;
    const int o_ar = o_r0 + (w >> 1) * 16 + r16;
    const int o_cr = o_r0 + (w >> 1) * 16 + lg * 4;
    const int o_c  = ((bid - 192) & 1) * 32 + (w & 1) * 16 + r16;

    for (int t = 0; t < HOR; ++t) {
        // -------- slot 1: xgd + gates --------
        if (bid < 64) {
            short8 xa0, xa1;
            if (t == 0) {
                xa0 = ld8(a.xb + ((size_t)g_arow * TX + TX - 1) * NX + lg * 8);
                xa1 = ld8(a.xb + ((size_t)g_arow * TX + TX - 1) * NX + 32 + lg * 8);
            } else {
                xa0 = ld8(a.ypb + (size_t)g_arow * NY + lg * 8);
                xa1 = ld8(a.ypb + (size_t)g_arow * NY + 32 + lg * 8);
            }
            floatx4 ax[3];
#pragma unroll
            for (int n = 0; n < 3; ++n) {
                ax[n] = floatx4{0.f, 0.f, 0.f, 0.f};
                ax[n] = mfma16(xa0, xw[0][n], ax[n]);
                ax[n] = mfma16(xa1, xw[1][n], ax[n]);
            }
#pragma unroll
            for (int j = 0; j < 4; ++j) {
                const float r  = sigmoidf_(ax[0][j] + cst[0][j] + hga[0][j] + dbhhv[0]);
                const float z  = sigmoidf_(ax[1][j] + cst[1][j] + hga[1][j] + dbhhv[1]);
                const float nn = tanhf(ax[2][j] + cst[2][j] + r * (hga[2][j] + dbhhv[2]));
                hd[j] = (1.f - z) * nn + z * hd[j];
                a.hdb[(size_t)(g_crow + j) * H + g_ic] = f2bf(hd[j]);
            }
        }
        __threadfence();
        gg.sync();

        // -------- slot 2: hga_next || MLP1 --------
        if (bid < 64) {
#pragma unroll
            for (int n = 0; n < 3; ++n) hga[n] = floatx4{0.f, 0.f, 0.f, 0.f};
#pragma unroll 4
            for (int c = 0; c < 16; ++c) {
                const short8 ha = ld8(a.hdb + (size_t)g_arow * H + c * 32 + lg * 8);
#pragma unroll
                for (int n = 0; n < 3; ++n) {
                    const short8 hw =
                        ld8(a.dWhhb + (size_t)(n * H + g_ic) * H + c * 32 + lg * 8);
                    hga[n] = mfma16(ha, hw, hga[n]);
                }
            }
        } else if (bid < 192) {
            floatx4 acc = floatx4{0.f, 0.f, 0.f, 0.f};
#pragma unroll 4
            for (int c = 0; c < 16; ++c) {
                const short8 av = ld8(a.hdb + (size_t)m1_ar * H + c * 32 + lg * 8);
                const short8 bv = ld8(a.dmW1b + (size_t)m1_c * H + c * 32 + lg * 8);
                acc = mfma16(av, bv, acc);
            }
            const float bia = a.dmb1[m1_c];
#pragma unroll
            for (int j = 0; j < 4; ++j) {
                float v = acc[j] + bia;
                if (v < 0.f) v = 0.f;
                a.hm1b[(size_t)(m1_cr + j) * M1 + m1_c] = f2bf(v);
            }
        }
        __threadfence();
        gg.sync();

        // -------- slot 3: MLP2 --------
        if (bid >= 128 && bid < 192) {
            floatx4 acc = floatx4{0.f, 0.f, 0.f, 0.f};
#pragma unroll 4
            for (int c = 0; c < 32; ++c) {
                const short8 av = ld8(a.hm1b + (size_t)m2_ar * M1 + c * 32 + lg * 8);
                const short8 bv = ld8(a.dmW2b + (size_t)m2_c * M1 + c * 32 + lg * 8);
                acc = mfma16(av, bv, acc);
            }
            const float bia = a.dmb2[m2_c];
#pragma unroll
            for (int j = 0; j < 4; ++j) {
                float v = acc[j] + bia;
                if (v < 0.f) v = 0.f;
                a.hm2b[(size_t)(m2_cr + j) * M2 + m2_c] = f2bf(v);
            }
        }
        __threadfence();
        gg.sync();

        // -------- slot 4: out GEMM -> y --------
        if (bid >= 192 && bid < 200) {
            floatx4 acc = floatx4{0.f, 0.f, 0.f, 0.f};
#pragma unroll 4
            for (int c = 0; c < 16; ++c) {
                const short8 av = ld8(a.hm2b + (size_t)o_ar * M2 + c * 32 + lg * 8);
                const short8 bv = ld8(a.doWb + (size_t)o_c * M2 + c * 32 + lg * 8);
                acc = mfma16(av, bv, acc);
            }
            const float bia = a.dob[o_c];
#pragma unroll
            for (int j = 0; j < 4; ++j) {
                const float v = acc[j] + bia;
                a.outp[(size_t)(o_cr + j) * (HOR * NY) + (size_t)t * NY + o_c] = v;
                a.ypb[(size_t)(o_cr + j) * NY + o_c] = f2bf(v);
            }
        }
        __threadfence();
        gg.sync();
    }
}

// ===========================================================================
extern "C" void kernel_launch(void* const* d_in, const int* in_sizes, int n_in,
                              void* d_out, int out_size, void* d_ws, size_t ws_size,
                              hipStream_t stream)
{
    const float* x      = (const float*)d_in[0];
    const float* y      = (const float*)d_in[1];
    const float* xf_bih = (const float*)d_in[4];
    const float* xf_bhh = (const float*)d_in[5];
    const float* xb_bih = (const float*)d_in[8];
    const float* xb_bhh = (const float*)d_in[9];
    const float* ef_bih = (const float*)d_in[12];
    const float* ef_bhh = (const float*)d_in[13];
    const float* eb_bih = (const float*)d_in[16];
    const float* eb_bhh = (const float*)d_in[17];
    const float* em_b1  = (const float*)d_in[19];
    const float* em_b2  = (const float*)d_in[21];
    const float* eo_b   = (const float*)d_in[23];
    const float* d_bih  = (const float*)d_in[26];
    const float* d_bhh  = (const float*)d_in[27];
    const float* dm_b1  = (const float*)d_in[29];
    const float* dm_b2  = (const float*)d_in[31];
    const float* do_b   = (const float*)d_in[33];
    float* out = (float*)d_out;

    // ---- workspace carve-up ----
    float* fp = (float*)d_ws;
    float* Hs     = fp; fp += 4 * (size_t)B * H;
    float* constb = fp; fp += (size_t)B * G3;

    unsigned short* up = (unsigned short*)fp;
    unsigned short* xb16  = up; up += (size_t)B * TX * NX;
    unsigned short* yb16  = up; up += (size_t)B * TY * NY;
    unsigned short* Hsb0  = up; up += 4 * (size_t)B * H;
    unsigned short* Hsb1  = up; up += 4 * (size_t)B * H;
    unsigned short* hdb   = up; up += (size_t)B * H;
    unsigned short* hcatb = up; up += (size_t)B * 2 * H;
    unsigned short* czb   = up; up += (size_t)B * 2 * H;
    unsigned short* h1b   = up; up += (size_t)B * M1;
    unsigned short* h2b   = up; up += (size_t)B * M2;
    unsigned short* hm1b  = up; up += (size_t)B * M1;
    unsigned short* hm2b  = up; up += (size_t)B * M2;
    unsigned short* ypb   = up; up += (size_t)B * NY;

    const int    widx[16] = {2, 3, 6, 7, 10, 11, 14, 15, 18, 20, 22, 24, 25, 28, 30, 32};
    const size_t wsz[16]  = {
        (size_t)G3 * NX, (size_t)G3 * H, (size_t)G3 * NX, (size_t)G3 * H,
        (size_t)G3 * NX, (size_t)G3 * H, (size_t)G3 * NX, (size_t)G3 * H,
        (size_t)M1 * 2 * H, (size_t)M2 * M1, (size_t)H * M2,
        (size_t)G3 * DIN, (size_t)G3 * H, (size_t)M1 * H, (size_t)M2 * M1,
        (size_t)NY * M2};
    unsigned short* wb[16];
    for (int i = 0; i < 16; ++i) { wb[i] = up; up += wsz[i]; }

    // ---- conversions (one launch) ----
    CvtArgs ca;
    for (int i = 0; i < 16; ++i) {
        ca.src[i] = (const float*)d_in[widx[i]];
        ca.dst[i] = wb[i];
        ca.n[i]   = (int)wsz[i];
    }
    ca.src[16] = x; ca.dst[16] = xb16; ca.n[16] = B * TX * NX;
    ca.src[17] = y; ca.dst[17] = yb16; ca.n[17] = B * TY * NY;
    k_cvt_all<<<dim3(64, 18), 256, 0, stream>>>(ca);

    hipMemsetAsync(Hsb0, 0, sizeof(unsigned short) * 4 * (size_t)B * H, stream);

    // ---- persistent encoder (cooperative, zero LDS) ----
    EncArgs ea;
    ea.xb = xb16; ea.yb = yb16; ea.Hsb0 = Hsb0; ea.Hsb1 = Hsb1; ea.Hs = Hs;
    ea.wih[0] = wb[0]; ea.whh[0] = wb[1];
    ea.wih[1] = wb[2]; ea.whh[1] = wb[3];
    ea.wih[2] = wb[4]; ea.whh[2] = wb[5];
    ea.wih[3] = wb[6]; ea.whh[3] = wb[7];
    ea.bih[0] = xf_bih; ea.bhh[0] = xf_bhh;
    ea.bih[1] = xb_bih; ea.bhh[1] = xb_bhh;
    ea.bih[2] = ef_bih; ea.bhh[2] = ef_bhh;
    ea.bih[3] = eb_bih; ea.bhh[3] = eb_bhh;
    void* eargs[] = {&ea};
    hipLaunchCooperativeKernel((void*)k_enc, dim3(256), dim3(512), eargs, 0, stream);

    // ---- bottleneck MLP (r2-proven one-shot GEMMs) ----
    k_sum_concat<<<B * H / 256, 256, 0, stream>>>(Hs, hcatb, czb);
    k_mgemm<128, 128><<<dim3(M1 / 128, B / 128), 256, 0, stream>>>(
        hcatb, 2 * H, wb[8], 2 * H, em_b1, nullptr, 0, h1b, M1, 2 * H, 1);
    k_mgemm<128, 128><<<dim3(M2 / 128, B / 128), 256, 0, stream>>>(
        h1b, M1, wb[9], M1, em_b2, nullptr, 0, h2b, M2, M1, 1);
    k_mgemm<128, 128><<<dim3(H / 128, B / 128), 256, 0, stream>>>(
        h2b, M2, wb[10], M2, eo_b, nullptr, 0, czb + H, 2 * H, M2, 0);
    k_mgemm<128, 128><<<dim3(G3 / 128, B / 128), 256, 0, stream>>>(
        czb, 2 * H, wb[11], DIN, d_bih, constb, G3, nullptr, 0, 2 * H, 0);

    // ---- persistent decoder (cooperative, zero LDS) ----
    DecArgs da;
    da.xb = xb16; da.ypb = ypb; da.hdb = hdb;
    da.constb = constb; da.dWihb = wb[11]; da.dWhhb = wb[12]; da.dbhh = d_bhh;
    da.dmW1b = wb[13]; da.dmb1 = dm_b1;
    da.dmW2b = wb[14]; da.dmb2 = dm_b2;
    da.doWb  = wb[15]; da.dob  = do_b;
    da.hm1b = hm1b; da.hm2b = hm2b; da.outp = out;
    void* dargs[] = {&da};
    hipLaunchCooperativeKernel((void*)k_dec, dim3(256), dim3(512), dargs, 0, stream);
}

// Round 5
// 6242.263 us; speedup vs baseline: 4.3823x; 4.3823x over previous
//
#include <hip/hip_runtime.h>
#include <math.h>

#define B   256
#define TX  50
#define TY  100
#define NX  64
#define NY  64
#define H   512
#define HOR 60
#define M1  1024
#define M2  512
#define G3  (3*H)        // 1536
#define DIN (2*H + NY)   // 1088

typedef __attribute__((ext_vector_type(8))) short short8;
typedef __attribute__((ext_vector_type(4))) float floatx4;

__device__ __forceinline__ unsigned short f2bf(float f) {
    union { float f; unsigned u; } v; v.f = f;
    return (unsigned short)((v.u + 0x7FFFu + ((v.u >> 16) & 1u)) >> 16);
}

__device__ __forceinline__ float sigmoidf_(float v) {
    return 1.f / (1.f + __expf(-v));
}

__device__ __forceinline__ short8 ld8(const unsigned short* p) {
    return *(const short8*)p;
}

__device__ __forceinline__ floatx4 mfma16(short8 a, short8 b, floatx4 c) {
    return __builtin_amdgcn_mfma_f32_16x16x32_bf16(a, b, c, 0, 0, 0);
}

__device__ __forceinline__ void gload_lds16(const void* g, void* lds) {
    __builtin_amdgcn_global_load_lds(
        (const __attribute__((address_space(1))) void*)g,
        (__attribute__((address_space(3))) void*)lds, 16, 0, 0);
}

// ===========================================================================
// r2-proven 128xBN MFMA GEMM body (one-shot layers), 256 threads.
// ===========================================================================
template<int BM, int BN>
__device__ __forceinline__ void mgemm_body(
    unsigned short* smA, unsigned short* smB,
    const unsigned short* __restrict__ A, int lda, int arow0,
    const unsigned short* __restrict__ W, int ldw, int wrow0,
    const float* __restrict__ bias,
    float* __restrict__ Cf, int ldcf,
    unsigned short* __restrict__ Cb, int ldcb,
    int K, int relu)
{
    constexpr int MF = BM / 32;
    constexpr int NF = BN / 32;
    const int tid = threadIdx.x;
    const int w  = tid >> 6, l = tid & 63;
    const int wr = w >> 1, wc = w & 1;
    const int lg = l >> 4, r16 = l & 15;

    floatx4 acc[MF][NF];
#pragma unroll
    for (int m = 0; m < MF; ++m)
#pragma unroll
        for (int n = 0; n < NF; ++n) acc[m][n] = floatx4{0.f, 0.f, 0.f, 0.f};

    for (int k0 = 0; k0 < K; k0 += 32) {
        __syncthreads();
#pragma unroll
        for (int i = 0; i < BM / 64; ++i) {
            const int ci = tid + i * 256;
            const int row = ci >> 2, pc = ci & 3;
            const int lc = pc ^ ((row >> 1) & 3);
            gload_lds16(A + (size_t)(arow0 + row) * lda + k0 + lc * 8,
                        (char*)smA + w * 1024 + i * 4096);
        }
#pragma unroll
        for (int i = 0; i < BN / 64; ++i) {
            const int ci = tid + i * 256;
            const int row = ci >> 2, pc = ci & 3;
            const int lc = pc ^ ((row >> 1) & 3);
            gload_lds16(W + (size_t)(wrow0 + row) * ldw + k0 + lc * 8,
                        (char*)smB + w * 1024 + i * 4096);
        }
        __syncthreads();

        short8 af[MF], bfr[NF];
#pragma unroll
        for (int m = 0; m < MF; ++m) {
            const int row = wr * (BM / 2) + m * 16 + r16;
            const int pc = lg ^ ((row >> 1) & 3);
            af[m] = *(const short8*)&smA[row * 32 + pc * 8];
        }
#pragma unroll
        for (int n = 0; n < NF; ++n) {
            const int row = wc * (BN / 2) + n * 16 + r16;
            const int pc = lg ^ ((row >> 1) & 3);
            bfr[n] = *(const short8*)&smB[row * 32 + pc * 8];
        }
#pragma unroll
        for (int m = 0; m < MF; ++m)
#pragma unroll
            for (int n = 0; n < NF; ++n)
                acc[m][n] = mfma16(af[m], bfr[n], acc[m][n]);
    }

#pragma unroll
    for (int m = 0; m < MF; ++m) {
#pragma unroll
        for (int n = 0; n < NF; ++n) {
#pragma unroll
            for (int j = 0; j < 4; ++j) {
                const int r = arow0 + wr * (BM / 2) + m * 16 + lg * 4 + j;
                const int c = wrow0 + wc * (BN / 2) + n * 16 + r16;
                float v = acc[m][n][j];
                if (bias) v += bias[c];
                if (relu && v < 0.f) v = 0.f;
                if (Cf) Cf[(size_t)r * ldcf + c] = v;
                if (Cb) Cb[(size_t)r * ldcb + c] = f2bf(v);
            }
        }
    }
}

template<int BM, int BN>
__global__ __launch_bounds__(256) void k_mgemm(
    const unsigned short* __restrict__ A, int lda,
    const unsigned short* __restrict__ W, int ldw,
    const float* __restrict__ bias,
    float* __restrict__ Cf, int ldcf,
    unsigned short* __restrict__ Cb, int ldcb,
    int K, int relu)
{
    __shared__ __align__(16) unsigned short smA[BM * 32];
    __shared__ __align__(16) unsigned short smB[BN * 32];
    mgemm_body<BM, BN>(smA, smB, A, lda, blockIdx.y * BM,
                       W, ldw, blockIdx.x * BN, bias,
                       Cf, ldcf, Cb, ldcb, K, relu);
}

// ===========================================================================
// fused fp32 -> bf16 conversion (18 segments, one launch)
// ===========================================================================
struct CvtArgs {
    const float* src[18];
    unsigned short* dst[18];
    int n[18];
};

__global__ __launch_bounds__(256) void k_cvt_all(CvtArgs a)
{
    const int seg = blockIdx.y;
    const float* s = a.src[seg];
    unsigned short* d = a.dst[seg];
    const int c4 = a.n[seg] >> 2;
    for (int i = blockIdx.x * 256 + threadIdx.x; i < c4; i += gridDim.x * 256) {
        float4 v = ((const float4*)s)[i];
        ushort4 o;
        o.x = f2bf(v.x); o.y = f2bf(v.y); o.z = f2bf(v.z); o.w = f2bf(v.w);
        ((ushort4*)d)[i] = o;
    }
}

// ===========================================================================
// h_x = hxf + hxb ; h_y = hef + heb ; hcat = [h_x,h_y] bf16 ; cz[:, :H] = h_x
// ===========================================================================
__global__ __launch_bounds__(256) void k_sum_concat(
    const float* __restrict__ Hs,
    unsigned short* __restrict__ hcatb, unsigned short* __restrict__ czb)
{
    const int idx = blockIdx.x * 256 + threadIdx.x;  // B*H
    const int b = idx / H, i = idx % H;
    const float hx = Hs[idx] + Hs[(size_t)B * H + idx];
    const float hy = Hs[2 * (size_t)B * H + idx] + Hs[3 * (size_t)B * H + idx];
    const unsigned short hxb = f2bf(hx);
    hcatb[(size_t)b * (2 * H) + i] = hxb;
    hcatb[(size_t)b * (2 * H) + H + i] = f2bf(hy);
    czb[(size_t)b * (2 * H) + i] = hxb;
}

// ===========================================================================
// Fused encoder step: ONE launch per time step.
// Grid (8 hid-slices, 2 batch-halves, njobs); 512 threads = 8 waves (2x4).
// Tile: 128 batch rows x 192 gate-cols (hid-slice of 64 x 3 gates,
// gate-interleaved per 16 cols so each lane owns its r/z/n triple).
// K-loop: 16 h-chunks (Whh) + 2 x-chunks (Wih); n-gate keeps a separate
// x-accumulator (r scales only hn). Gates fused in epilogue; h fp32 state in
// global (read+write each step), bf16 ping-pong for the next step's GEMM.
// ===========================================================================
struct EncP {
    const unsigned short *xb, *yb;
    unsigned short *Hsb0, *Hsb1;
    float* Hs;
    const unsigned short *wih[4], *whh[4];
    const float *bih[4], *bhh[4];
    int t, job0;
};

__global__ __launch_bounds__(512) void k_enc_step(EncP p)
{
    __shared__ __align__(16) char smA[8192];    // 128 x 32 bf16
    __shared__ __align__(16) char smB[12288];   // 192 x 32 bf16
    const int job = p.job0 + blockIdx.z;
    const int h0 = blockIdx.x * 64;
    const int row0 = blockIdx.y * 128;
    const int tid = threadIdx.x;
    const int w = tid >> 6, l = tid & 63;
    const int lg = l >> 4, r16 = l & 15;
    const int wrh = w >> 2, wcg = w & 3;
    const int T = (job < 2) ? TX : TY;
    const int tt = (job & 1) ? (T - 1 - p.t) : p.t;
    const unsigned short* xsrc = (job < 2) ? p.xb : p.yb;
    const unsigned short* wihg = p.wih[job];
    const unsigned short* whhg = p.whh[job];
    const unsigned short* hin =
        ((p.t & 1) ? p.Hsb1 : p.Hsb0) + (size_t)job * B * H;
    unsigned short* hout =
        ((p.t & 1) ? p.Hsb0 : p.Hsb1) + (size_t)job * B * H;

    // staging index math (16B chunks, XOR-swizzled logical k-chunk)
    const int sAr = tid >> 2;
    const int sAl = (tid & 3) ^ ((sAr >> 1) & 3);
    const int f0 = sAr >> 4;                       // B iter0 uses same row id
    const int W0 = (f0 % 3) * H + h0 + (f0 / 3) * 16 + (sAr & 15);
    const int sB1r = 128 + (tid >> 2);             // tid<256 only
    const int sB1l = (tid & 3) ^ ((sB1r >> 1) & 3);
    const int f1 = sB1r >> 4;
    const int W1 = (f1 % 3) * H + h0 + (f1 / 3) * 16 + (sB1r & 15);

    floatx4 am[4][3], axn[4];
#pragma unroll
    for (int m = 0; m < 4; ++m) {
        axn[m] = floatx4{0.f, 0.f, 0.f, 0.f};
#pragma unroll
        for (int g = 0; g < 3; ++g) am[m][g] = floatx4{0.f, 0.f, 0.f, 0.f};
    }

    for (int ck = 0; ck < 18; ++ck) {
        __syncthreads();
        if (ck < 16) {
            gload_lds16(hin + (size_t)(row0 + sAr) * H + ck * 32 + sAl * 8,
                        smA + tid * 16);
            gload_lds16(whhg + (size_t)W0 * H + ck * 32 + sAl * 8,
                        smB + tid * 16);
            if (tid < 256)
                gload_lds16(whhg + (size_t)W1 * H + ck * 32 + sB1l * 8,
                            smB + 8192 + tid * 16);
        } else {
            const int kk = (ck - 16) * 32;
            gload_lds16(xsrc + ((size_t)(row0 + sAr) * T + tt) * NX + kk + sAl * 8,
                        smA + tid * 16);
            gload_lds16(wihg + (size_t)W0 * NX + kk + sAl * 8,
                        smB + tid * 16);
            if (tid < 256)
                gload_lds16(wihg + (size_t)W1 * NX + kk + sB1l * 8,
                            smB + 8192 + tid * 16);
        }
        __syncthreads();

        short8 af[4], bf[3];
#pragma unroll
        for (int m = 0; m < 4; ++m) {
            const int row = wrh * 64 + m * 16 + r16;
            af[m] = *(const short8*)(smA + row * 64 + ((lg ^ ((row >> 1) & 3)) << 4));
        }
#pragma unroll
        for (int g = 0; g < 3; ++g) {
            const int rb = wcg * 48 + g * 16 + r16;
            bf[g] = *(const short8*)(smB + rb * 64 + ((lg ^ ((rb >> 1) & 3)) << 4));
        }
        if (ck < 16) {
#pragma unroll
            for (int m = 0; m < 4; ++m) {
                am[m][0] = mfma16(af[m], bf[0], am[m][0]);
                am[m][1] = mfma16(af[m], bf[1], am[m][1]);
                am[m][2] = mfma16(af[m], bf[2], am[m][2]);
            }
        } else {
#pragma unroll
            for (int m = 0; m < 4; ++m) {
                am[m][0] = mfma16(af[m], bf[0], am[m][0]);
                am[m][1] = mfma16(af[m], bf[1], am[m][1]);
                axn[m]   = mfma16(af[m], bf[2], axn[m]);
            }
        }
    }

    // ---- gate epilogue ----
    const int u = h0 + wcg * 16 + r16;
    const float bi0 = p.bih[job][u]        + p.bhh[job][u];
    const float bi1 = p.bih[job][H + u]    + p.bhh[job][H + u];
    const float bi2 = p.bih[job][2 * H + u];
    const float bh2 = p.bhh[job][2 * H + u];
    float* HsJ = p.Hs + (size_t)job * B * H;
#pragma unroll
    for (int m = 0; m < 4; ++m) {
#pragma unroll
        for (int j = 0; j < 4; ++j) {
            const int br = row0 + wrh * 64 + m * 16 + lg * 4 + j;
            const float rr = sigmoidf_(am[m][0][j] + bi0);
            const float zz = sigmoidf_(am[m][1][j] + bi1);
            const float nn = tanhf(axn[m][j] + bi2 + rr * (am[m][2][j] + bh2));
            const float hold = HsJ[(size_t)br * H + u];
            const float hv = (1.f - zz) * nn + zz * hold;
            HsJ[(size_t)br * H + u] = hv;
            hout[(size_t)br * H + u] = f2bf(hv);
        }
    }
}

// ===========================================================================
// Fused decoder step kernel kD: out-GEMM (y_{t-1}) + xgd (K=64) + gates.
// Grid (8 hid-slices, 2 batch-halves), 512 threads. Each block computes the
// full 64-col y for its 128 rows (8x redundant out-GEMM, saves a launch);
// y staged in XOR-swizzled LDS, consumed as the xgd A-operand.
// mode: 0 = t==0 (y from x[:, -1]), 1 = normal, 2 = out-only (final y).
// ===========================================================================
struct DecP {
    const unsigned short* xb;
    unsigned short* hdb;
    float* hd;
    const float* hga;
    const float* constb;
    const unsigned short* dWihb;
    const float* dbhh;
    const unsigned short* doWb; const float* dob;
    const unsigned short* hm2b;
    float* outp;
    int mode, tprev;
};

__global__ __launch_bounds__(512) void k_dec_step(DecP p)
{
    __shared__ __align__(16) unsigned short ytile[128 * 64];
    const int tid = threadIdx.x;
    const int w = tid >> 6, l = tid & 63;
    const int lg = l >> 4, r16 = l & 15;
    const int row0 = blockIdx.y * 128;
    const int h0 = blockIdx.x * 64;

    if (p.mode != 0) {
        // phase A: y = hm2b @ do_W^T + do_b  (128 x 64, K=512)
        const int wrA = w >> 1, wcA = w & 1;   // 4 x 2 waves, 32x32 tiles
        floatx4 acc[2][2];
#pragma unroll
        for (int mA = 0; mA < 2; ++mA)
#pragma unroll
            for (int nA = 0; nA < 2; ++nA) acc[mA][nA] = floatx4{0.f, 0.f, 0.f, 0.f};
        for (int ck = 0; ck < 16; ++ck) {
            short8 av[2], bv[2];
#pragma unroll
            for (int mA = 0; mA < 2; ++mA)
                av[mA] = ld8(p.hm2b + (size_t)(row0 + wrA * 32 + mA * 16 + r16) * M2
                                     + ck * 32 + lg * 8);
#pragma unroll
            for (int nA = 0; nA < 2; ++nA)
                bv[nA] = ld8(p.doWb + (size_t)(wcA * 32 + nA * 16 + r16) * M2
                                     + ck * 32 + lg * 8);
#pragma unroll
            for (int mA = 0; mA < 2; ++mA)
#pragma unroll
                for (int nA = 0; nA < 2; ++nA)
                    acc[mA][nA] = mfma16(av[mA], bv[nA], acc[mA][nA]);
        }
#pragma unroll
        for (int mA = 0; mA < 2; ++mA) {
#pragma unroll
            for (int nA = 0; nA < 2; ++nA) {
#pragma unroll
                for (int j = 0; j < 4; ++j) {
                    const int rr = wrA * 32 + mA * 16 + lg * 4 + j;
                    const int cc = wcA * 32 + nA * 16 + r16;
                    const float v = acc[mA][nA][j] + p.dob[cc];
                    if (blockIdx.x == 0)
                        p.outp[(size_t)(row0 + rr) * (HOR * NY)
                               + (size_t)p.tprev * NY + cc] = v;
                    *(unsigned short*)((char*)ytile + rr * 128
                        + ((cc * 2) ^ ((rr & 7) << 4))) = f2bf(v);
                }
            }
        }
    } else {
        for (int i = tid; i < 128 * 64; i += 512) {
            const int rr = i >> 6, cc = i & 63;
            const unsigned short v =
                p.xb[((size_t)(row0 + rr) * TX + TX - 1) * NX + cc];
            *(unsigned short*)((char*)ytile + rr * 128
                + ((cc * 2) ^ ((rr & 7) << 4))) = v;
        }
    }
    if (p.mode == 2) return;
    __syncthreads();

    // phase B: xgd (128 x 192 gate-cols, K=64) + gates
    const int wrh = w >> 2, wcg = w & 3;
    short8 ya[2][4];
#pragma unroll
    for (int ks = 0; ks < 2; ++ks)
#pragma unroll
        for (int m = 0; m < 4; ++m) {
            const int row = wrh * 64 + m * 16 + r16;
            const int k0 = ks * 32 + lg * 8;
            ya[ks][m] = *(const short8*)((char*)ytile + row * 128
                          + ((k0 * 2) ^ ((row & 7) << 4)));
        }
    short8 xw[2][3];
#pragma unroll
    for (int ks = 0; ks < 2; ++ks)
#pragma unroll
        for (int g = 0; g < 3; ++g)
            xw[ks][g] = ld8(p.dWihb + (size_t)(g * H + h0 + wcg * 16 + r16) * DIN
                                    + 2 * H + ks * 32 + lg * 8);
    floatx4 ag[4][3];
#pragma unroll
    for (int m = 0; m < 4; ++m)
#pragma unroll
        for (int g = 0; g < 3; ++g) ag[m][g] = floatx4{0.f, 0.f, 0.f, 0.f};
#pragma unroll
    for (int ks = 0; ks < 2; ++ks)
#pragma unroll
        for (int m = 0; m < 4; ++m)
#pragma unroll
            for (int g = 0; g < 3; ++g)
                ag[m][g] = mfma16(ya[ks][m], xw[ks][g], ag[m][g]);

    const int u = h0 + wcg * 16 + r16;
    const float db0 = p.dbhh[u], db1 = p.dbhh[H + u], db2 = p.dbhh[2 * H + u];
#pragma unroll
    for (int m = 0; m < 4; ++m) {
#pragma unroll
        for (int j = 0; j < 4; ++j) {
            const int b = row0 + wrh * 64 + m * 16 + lg * 4 + j;
            const size_t g3 = (size_t)b * G3;
            const float xr = ag[m][0][j] + p.constb[g3 + u];
            const float xz = ag[m][1][j] + p.constb[g3 + H + u];
            const float xn = ag[m][2][j] + p.constb[g3 + 2 * H + u];
            const float hr = p.hga[g3 + u] + db0;
            const float hz = p.hga[g3 + H + u] + db1;
            const float hn = p.hga[g3 + 2 * H + u] + db2;
            const float rr = sigmoidf_(xr + hr);
            const float zz = sigmoidf_(xz + hz);
            const float nn = tanhf(xn + rr * hn);
            const float hold = p.hd[(size_t)b * H + u];
            const float hv = (1.f - zz) * nn + zz * hold;
            p.hd[(size_t)b * H + u] = hv;
            p.hdb[(size_t)b * H + u] = f2bf(hv);
        }
    }
}

// ===========================================================================
// kB: hga_{t+1} (24 blocks) || MLP1 (16 blocks) in ONE launch, 256 threads.
// ===========================================================================
__global__ __launch_bounds__(256) void k_dec_bk(
    const unsigned short* __restrict__ hdb,
    const unsigned short* __restrict__ dWhhb,
    const unsigned short* __restrict__ dmW1b, const float* __restrict__ dmb1,
    float* __restrict__ hga, unsigned short* __restrict__ hm1b)
{
    __shared__ __align__(16) unsigned short smA[128 * 32];
    __shared__ __align__(16) unsigned short smB[128 * 32];
    const int bid = blockIdx.x;
    if (bid < 24) {
        const int cx = bid >> 1, ry = bid & 1;
        mgemm_body<128, 128>(smA, smB, hdb, H, ry * 128, dWhhb, H, cx * 128,
                             nullptr, hga, G3, nullptr, 0, H, 0);
    } else {
        const int b2 = bid - 24;
        const int cx = b2 >> 1, ry = b2 & 1;
        mgemm_body<128, 128>(smA, smB, hdb, H, ry * 128, dmW1b, H, cx * 128,
                             dmb1, nullptr, 0, hm1b, M1, H, 1);
    }
}

// ===========================================================================
extern "C" void kernel_launch(void* const* d_in, const int* in_sizes, int n_in,
                              void* d_out, int out_size, void* d_ws, size_t ws_size,
                              hipStream_t stream)
{
    const float* x      = (const float*)d_in[0];
    const float* y      = (const float*)d_in[1];
    const float* xf_bih = (const float*)d_in[4];
    const float* xf_bhh = (const float*)d_in[5];
    const float* xb_bih = (const float*)d_in[8];
    const float* xb_bhh = (const float*)d_in[9];
    const float* ef_bih = (const float*)d_in[12];
    const float* ef_bhh = (const float*)d_in[13];
    const float* eb_bih = (const float*)d_in[16];
    const float* eb_bhh = (const float*)d_in[17];
    const float* em_b1  = (const float*)d_in[19];
    const float* em_b2  = (const float*)d_in[21];
    const float* eo_b   = (const float*)d_in[23];
    const float* d_bih  = (const float*)d_in[26];
    const float* d_bhh  = (const float*)d_in[27];
    const float* dm_b1  = (const float*)d_in[29];
    const float* dm_b2  = (const float*)d_in[31];
    const float* do_b   = (const float*)d_in[33];
    float* out = (float*)d_out;

    // ---- workspace carve-up ----
    float* fp = (float*)d_ws;
    float* Hs     = fp; fp += 4 * (size_t)B * H;
    float* hd     = fp; fp += (size_t)B * H;
    float* hga    = fp; fp += (size_t)B * G3;
    float* constb = fp; fp += (size_t)B * G3;

    unsigned short* up = (unsigned short*)fp;
    unsigned short* xb16  = up; up += (size_t)B * TX * NX;
    unsigned short* yb16  = up; up += (size_t)B * TY * NY;
    unsigned short* Hsb0  = up; up += 4 * (size_t)B * H;
    unsigned short* Hsb1  = up; up += 4 * (size_t)B * H;
    unsigned short* hdb   = up; up += (size_t)B * H;
    unsigned short* hcatb = up; up += (size_t)B * 2 * H;
    unsigned short* czb   = up; up += (size_t)B * 2 * H;
    unsigned short* h1b   = up; up += (size_t)B * M1;
    unsigned short* h2b   = up; up += (size_t)B * M2;
    unsigned short* hm1b  = up; up += (size_t)B * M1;
    unsigned short* hm2b  = up; up += (size_t)B * M2;

    const int    widx[16] = {2, 3, 6, 7, 10, 11, 14, 15, 18, 20, 22, 24, 25, 28, 30, 32};
    const size_t wsz[16]  = {
        (size_t)G3 * NX, (size_t)G3 * H, (size_t)G3 * NX, (size_t)G3 * H,
        (size_t)G3 * NX, (size_t)G3 * H, (size_t)G3 * NX, (size_t)G3 * H,
        (size_t)M1 * 2 * H, (size_t)M2 * M1, (size_t)H * M2,
        (size_t)G3 * DIN, (size_t)G3 * H, (size_t)M1 * H, (size_t)M2 * M1,
        (size_t)NY * M2};
    unsigned short* wb[16];
    for (int i = 0; i < 16; ++i) { wb[i] = up; up += wsz[i]; }

    // ---- conversions + state init ----
    CvtArgs ca;
    for (int i = 0; i < 16; ++i) {
        ca.src[i] = (const float*)d_in[widx[i]];
        ca.dst[i] = wb[i];
        ca.n[i]   = (int)wsz[i];
    }
    ca.src[16] = x; ca.dst[16] = xb16; ca.n[16] = B * TX * NX;
    ca.src[17] = y; ca.dst[17] = yb16; ca.n[17] = B * TY * NY;
    k_cvt_all<<<dim3(64, 18), 256, 0, stream>>>(ca);

    hipMemsetAsync(Hs,   0, sizeof(float) * 4 * (size_t)B * H, stream);
    hipMemsetAsync(Hsb0, 0, sizeof(unsigned short) * 4 * (size_t)B * H, stream);
    hipMemsetAsync(hd,   0, sizeof(float) * (size_t)B * H, stream);
    hipMemsetAsync(hga,  0, sizeof(float) * (size_t)B * G3, stream);

    // ---- encoder: 1 fused launch per step ----
    EncP ep;
    ep.xb = xb16; ep.yb = yb16; ep.Hsb0 = Hsb0; ep.Hsb1 = Hsb1; ep.Hs = Hs;
    ep.wih[0] = wb[0]; ep.whh[0] = wb[1];
    ep.wih[1] = wb[2]; ep.whh[1] = wb[3];
    ep.wih[2] = wb[4]; ep.whh[2] = wb[5];
    ep.wih[3] = wb[6]; ep.whh[3] = wb[7];
    ep.bih[0] = xf_bih; ep.bhh[0] = xf_bhh;
    ep.bih[1] = xb_bih; ep.bhh[1] = xb_bhh;
    ep.bih[2] = ef_bih; ep.bhh[2] = ef_bhh;
    ep.bih[3] = eb_bih; ep.bhh[3] = eb_bhh;
    for (int t = 0; t < TY; ++t) {
        ep.t = t;
        ep.job0 = (t < TX) ? 0 : 2;
        const int nj = (t < TX) ? 4 : 2;
        k_enc_step<<<dim3(8, 2, nj), 512, 0, stream>>>(ep);
    }

    // ---- bottleneck MLP ----
    k_sum_concat<<<B * H / 256, 256, 0, stream>>>(Hs, hcatb, czb);
    k_mgemm<128, 128><<<dim3(M1 / 128, B / 128), 256, 0, stream>>>(
        hcatb, 2 * H, wb[8], 2 * H, em_b1, nullptr, 0, h1b, M1, 2 * H, 1);
    k_mgemm<128, 128><<<dim3(M2 / 128, B / 128), 256, 0, stream>>>(
        h1b, M1, wb[9], M1, em_b2, nullptr, 0, h2b, M2, M1, 1);
    k_mgemm<128, 128><<<dim3(H / 128, B / 128), 256, 0, stream>>>(
        h2b, M2, wb[10], M2, eo_b, nullptr, 0, czb + H, 2 * H, M2, 0);
    k_mgemm<128, 128><<<dim3(G3 / 128, B / 128), 256, 0, stream>>>(
        czb, 2 * H, wb[11], DIN, d_bih, constb, G3, nullptr, 0, 2 * H, 0);

    // ---- decoder: 3 launches per step ----
    DecP dp;
    dp.xb = xb16; dp.hdb = hdb; dp.hd = hd; dp.hga = hga; dp.constb = constb;
    dp.dWihb = wb[11]; dp.dbhh = d_bhh;
    dp.doWb = wb[15]; dp.dob = do_b;
    dp.hm2b = hm2b; dp.outp = out;
    for (int t = 0; t < HOR; ++t) {
        dp.mode = (t == 0) ? 0 : 1;
        dp.tprev = t - 1;
        k_dec_step<<<dim3(8, 2), 512, 0, stream>>>(dp);
        k_dec_bk<<<40, 256, 0, stream>>>(hdb, wb[12], wb[13], dm_b1, hga, hm1b);
        k_mgemm<128, 64><<<dim3(M2 / 64, B / 128), 256, 0, stream>>>(
            hm1b, M1, wb[14], M1, dm_b2, nullptr, 0, hm2b, M2, M1, 1);
    }
    dp.mode = 2;
    dp.tprev = HOR - 1;
    k_dec_step<<<dim3(1, 2), 512, 0, stream>>>(dp);
}